// Round 5
// baseline (620.861 us; speedup 1.0000x reference)
//
#include <hip/hip_runtime.h>
#include <hip/hip_bf16.h>

#define B_  16
#define C_  64
#define H_  128
#define W_  128
#define HW_ (H_*W_)
#define E_  8

// ws layout (float offsets)
#define WS_LOGITS 0       // 128 floats
#define WS_SEL    128     // 32 ints: e1[16] then e2[16]

// ---- sentinel: encode a failed host-side assertion in the absmax ----
__global__ void k_sentinel(float* out, float v){
    if (blockIdx.x == 0 && threadIdx.x == 0) out[0] = v;
}

// ================= k1p: router conv, channel-split partials =================
// 16x64 pixel tile, 8 channel groups of 8 channels (2048 blocks, 8/CU, 32 waves/CU).
// T14 staging: global->regs issued BEFORE compute, ds_write AFTER (latency hides
// under the conv FMAs). Double-buffered LDS. Partials go to d_out scratch.
#define R_TH 16
#define R_TW 64
#define R_HH (R_TH+6)    // 22
#define R_HW (R_TW+6)    // 70
#define R_LS 76          // LDS row stride
#define R_HN (R_HH*R_HW) // 1540
#define RG_CH 8          // channels per group
#define RG_N  8          // groups
#define R_ST  7          // staging reg slots (1540/256 -> 7)

__global__ __launch_bounds__(256, 8) void k1p(const float* __restrict__ x,
                                              const float* __restrict__ rw,
                                              const float* __restrict__ rb,
                                              float* __restrict__ part){
    __shared__ __align__(16) float tile[2][R_HH*R_LS];   // 2 x 6688 B

    int id = blockIdx.x;
    int g   = id & 7; id >>= 3;      // channel group (8)
    int txt = id & 1; id >>= 1;      // col half
    int tyt = id & 7; id >>= 3;      // 16-row band
    int b   = id;                    // 16
    int row0 = tyt*R_TH, col0 = txt*R_TW;
    int tx = threadIdx.x & 15, ty = threadIdx.x >> 4;
    int row  = row0 + ty;
    int colb = col0 + 4*tx;

    const float* xg  = x  + ((size_t)(b*C_) + g*RG_CH)*HW_;
    const float* wgr = rw + g*RG_CH*49;

    float stv[R_ST]; int sto[R_ST];

    auto load_st = [&](int ch){
        const float* xc = xg + (size_t)ch*HW_;
        #pragma unroll
        for (int q = 0; q < R_ST; ++q){
            int i = (int)threadIdx.x + q*256;
            float v = 0.f; int off = 0;
            if (q < R_ST-1 || i < R_HN){
                int hr = i / R_HW, hc = i - hr*R_HW;
                off = hr*R_LS + hc;
                int gr = row0 + hr - 3, gc = col0 + hc - 3;
                if ((unsigned)gr < (unsigned)H_ && (unsigned)gc < (unsigned)W_)
                    v = xc[gr*W_ + gc];
            }
            stv[q] = v; sto[q] = off;
        }
    };
    auto write_st = [&](float* dst){
        #pragma unroll
        for (int q = 0; q < R_ST; ++q){
            int i = (int)threadIdx.x + q*256;
            if (q < R_ST-1 || i < R_HN) dst[sto[q]] = stv[q];
        }
    };

    float acc[4] = {0.f,0.f,0.f,0.f};

    load_st(0); write_st(tile[0]); __syncthreads();

    for (int ch = 0; ch < RG_CH; ++ch){
        if (ch + 1 < RG_CH) load_st(ch+1);          // issue loads early (T14)

        const float* wr = wgr + ch*49;              // block-uniform -> SGPR
        const float* tb = tile[ch & 1];
        #pragma unroll
        for (int ky = 0; ky < 7; ++ky){
            const float* trp = &tb[(ty+ky)*R_LS + 4*tx];
            float4 va = *(const float4*)(trp);
            float4 vb = *(const float4*)(trp+4);
            float2 vc = *(const float2*)(trp+8);
            float win[10] = {va.x,va.y,va.z,va.w, vb.x,vb.y,vb.z,vb.w, vc.x,vc.y};
            #pragma unroll
            for (int kx = 0; kx < 7; ++kx){
                float w = wr[ky*7+kx];
                acc[0] += w*win[kx+0];
                acc[1] += w*win[kx+1];
                acc[2] += w*win[kx+2];
                acc[3] += w*win[kx+3];
            }
        }
        if (ch + 1 < RG_CH){
            write_st(tile[(ch+1) & 1]);             // vmcnt waits land here
            __syncthreads();
        }
    }

    if (g == 0){
        float rbv = rb[0];
        acc[0]+=rbv; acc[1]+=rbv; acc[2]+=rbv; acc[3]+=rbv;
    }
    float* pr = part + (size_t)g*(B_*HW_);
    size_t base = (size_t)b*HW_ + (size_t)row*W_ + colb;
    #pragma unroll
    for (int p = 0; p < 4; ++p) pr[base+p] = acc[p];
}

// ---- kg: logits[b,e] = sum_hw (sum_g part[g,b,hw]) * wg[hw,e] ----
__global__ __launch_bounds__(256) void kg(const float* __restrict__ part,
                                          const float* __restrict__ wg,
                                          float* __restrict__ logits){
    __shared__ float red[256];
    int b = blockIdx.x >> 3, e = blockIdx.x & 7;   // 128 blocks
    const float* p0 = part + (size_t)b*HW_;
    float s = 0.f;
    for (int hw = threadIdx.x; hw < HW_; hw += 256){
        float rv = 0.f;
        #pragma unroll
        for (int gg = 0; gg < RG_N; ++gg)
            rv += p0[hw + (size_t)gg*(B_*HW_)];
        s += rv * wg[(size_t)hw*E_ + e];
    }
    red[threadIdx.x] = s;
    __syncthreads();
    for (int off = 128; off > 0; off >>= 1){
        if (threadIdx.x < off) red[threadIdx.x] += red[threadIdx.x + off];
        __syncthreads();
    }
    if (threadIdx.x == 0) logits[b*E_+e] = red[0];
}

// ---- k2: parallel top-2 gating + loss (16 lanes for top-2, 8 for imp/cnt) ----
__global__ void k2_gating(const float* __restrict__ logits,
                          int* __restrict__ sel,
                          float* __restrict__ out){
    __shared__ float g1s[B_], g2s[B_];
    __shared__ int   i1s[B_], i2s[B_];
    __shared__ float impS[E_], cntS[E_];
    int t = threadIdx.x;
    if (t < B_){
        const float* l = logits + t*E_;
        int i1 = 0;
        #pragma unroll
        for (int e = 1; e < E_; ++e) if (l[e] > l[i1]) i1 = e;   // ties -> lowest idx
        int i2 = (i1 == 0) ? 1 : 0;
        #pragma unroll
        for (int e = 0; e < E_; ++e) if (e != i1 && l[e] > l[i2]) i2 = e;
        float ex = expf(l[i2] - l[i1]);
        float g1 = 1.f/(1.f+ex), g2 = ex/(1.f+ex);
        sel[t] = i1; sel[B_ + t] = i2;
        g1s[t] = g1; g2s[t] = g2; i1s[t] = i1; i2s[t] = i2;
    }
    __syncthreads();
    if (t < E_){
        float im = 0.f, cn = 0.f;
        #pragma unroll
        for (int bb = 0; bb < B_; ++bb){
            im += (i1s[bb]==t ? g1s[bb] : 0.f) + (i2s[bb]==t ? g2s[bb] : 0.f);
            cn += (i1s[bb]==t ? 1.f : 0.f)     + (i2s[bb]==t ? 1.f : 0.f);
        }
        impS[t] = im; cntS[t] = cn;
    }
    __syncthreads();
    if (t == 0){
        float m1 = 0.f, m2 = 0.f;
        for (int e = 0; e < E_; ++e){ m1 += impS[e]; m2 += cntS[e]; }
        m1 *= (1.f/E_); m2 *= (1.f/E_);
        float v1 = 0.f, v2 = 0.f;
        for (int e = 0; e < E_; ++e){
            float d1 = impS[e] - m1; v1 += d1*d1;
            float d2 = cntS[e] - m2; v2 += d2*d2;
        }
        v1 *= (1.f/(E_-1)); v2 *= (1.f/(E_-1));
        float loss = (v1/(m1*m1 + 1e-10f) + v2/(m2*m2 + 1e-10f)) * 0.01f;
        out[(size_t)B_*HW_*C_] = loss;
    }
}

// ================= k3: tiled experts+shared conv + LSE combine =================
// 16x16 pixel tile, 8 chunks of 8 channels. LDS 25 KB -> up to 6 blocks/CU.
// Thread = (c8, trow, half): 8 output cols/thread -> 24 accs live (fits regs).
// T14 staging: global->regs before compute, ds_write after barrier.
#define C3_NCH 8
#define C3_CS  28              // LDS col stride (22 used)
#define C3_CHS (22*C3_CS)      // 616 floats/channel plane (mod 32 = 8: banks ok)
#define C3_WST 56              // 7 ky x 8 (kx 0..6 + zero pad)
#define C3_TN  (C3_NCH*22*22)  // 3872
#define C3_WN  (3*C3_NCH*C3_WST) // 1344
#define C3_ST  16
#define C3_SW  6

__global__ __launch_bounds__(256, 4) void k3_tiled(const float* __restrict__ x,
                                                   const float* __restrict__ ew,
                                                   const float* __restrict__ eb,
                                                   const float* __restrict__ sw,
                                                   const float* __restrict__ sb,
                                                   const int* __restrict__ sel,
                                                   float* __restrict__ out){
    __shared__ __align__(16) float tile[C3_NCH*C3_CHS];   // 4928 f = 19.7 KB
    __shared__ __align__(16) float wbuf[C3_WN];           // 1344 f =  5.4 KB

    int id = blockIdx.x;
    int cx = id & 7; id >>= 3;
    int cy = id & 7; id >>= 3;
    int b  = id;                           // 1024 blocks
    int r0 = cy*16, c0 = cx*16;

    int c8   = threadIdx.x & 7;            // channel within chunk
    int slot = threadIdx.x >> 3;           // 0..31
    int trow = slot >> 1;                  // 0..15
    int colt = (slot & 1) * 8;             // col half: 0 or 8

    int e1 = sel[b], e2 = sel[B_ + b];

    float stv[C3_ST];
    float swv[C3_SW];

    // offsets recomputed at write time (keeps VGPR pressure down)
    auto load_regs = [&](int cc0){
        #pragma unroll
        for (int q = 0; q < C3_ST; ++q){
            int i = (int)threadIdx.x + q*256;
            float v = 0.f;
            if (q < C3_ST-1 || i < C3_TN){
                int ci = i / 484; int rem = i - ci*484;
                int hr = rem / 22, hc = rem - hr*22;
                int gr = r0 + hr - 3, gc = c0 + hc - 3;
                if ((unsigned)gr < (unsigned)H_ && (unsigned)gc < (unsigned)W_)
                    v = x[((size_t)(b*C_ + cc0 + ci))*HW_ + gr*W_ + gc];
            }
            stv[q] = v;
        }
        #pragma unroll
        for (int q = 0; q < C3_SW; ++q){
            int i = (int)threadIdx.x + q*256;
            float v = 0.f;
            if (q < C3_SW-1 || i < C3_WN){
                int which = i / 448;       // 8ch*56
                int rem = i - which*448;
                int wc = rem / C3_WST;
                int tt = rem - wc*C3_WST;
                int ky = tt >> 3, kx = tt & 7;
                if (kx < 7){
                    int tap = ky*7 + kx;
                    if (which == 0)      v = ew[((size_t)(e1*C_ + cc0 + wc))*49 + tap];
                    else if (which == 1) v = ew[((size_t)(e2*C_ + cc0 + wc))*49 + tap];
                    else                 v = sw[((size_t)(cc0 + wc))*49 + tap];
                }
            }
            swv[q] = v;
        }
    };
    auto write_regs = [&](){
        #pragma unroll
        for (int q = 0; q < C3_ST; ++q){
            int i = (int)threadIdx.x + q*256;
            if (q < C3_ST-1 || i < C3_TN){
                int ci = i / 484; int rem = i - ci*484;
                int hr = rem / 22, hc = rem - hr*22;
                tile[ci*C3_CHS + hr*C3_CS + hc] = stv[q];
            }
        }
        #pragma unroll
        for (int q = 0; q < C3_SW; ++q){
            int i = (int)threadIdx.x + q*256;
            if (q < C3_SW-1 || i < C3_WN) wbuf[i] = swv[q];
        }
    };

    load_regs(0); write_regs(); __syncthreads();

    for (int k = 0; k < 8; ++k){
        int cc0 = k*C3_NCH;
        if (k < 7) load_regs(cc0 + C3_NCH);    // issue next-chunk loads early

        float a1[8], a2[8], a3[8];
        #pragma unroll
        for (int c = 0; c < 8; ++c){ a1[c]=0.f; a2[c]=0.f; a3[c]=0.f; }

        const float* tb = tile + c8*C3_CHS;
        #pragma unroll
        for (int ky = 0; ky < 7; ++ky){
            const float* trp = tb + (trow+ky)*C3_CS + colt;
            float win[16];
            #pragma unroll
            for (int q = 0; q < 4; ++q){
                float4 v4 = *(const float4*)(trp + 4*q);
                win[4*q+0]=v4.x; win[4*q+1]=v4.y; win[4*q+2]=v4.z; win[4*q+3]=v4.w;
            }
            float u1[7], u2[7], u3[7];
            { const float* wp = wbuf + (0*C3_NCH + c8)*C3_WST + ky*8;
              float4 a = *(const float4*)wp, c4 = *(const float4*)(wp+4);
              u1[0]=a.x;u1[1]=a.y;u1[2]=a.z;u1[3]=a.w;u1[4]=c4.x;u1[5]=c4.y;u1[6]=c4.z; }
            { const float* wp = wbuf + (1*C3_NCH + c8)*C3_WST + ky*8;
              float4 a = *(const float4*)wp, c4 = *(const float4*)(wp+4);
              u2[0]=a.x;u2[1]=a.y;u2[2]=a.z;u2[3]=a.w;u2[4]=c4.x;u2[5]=c4.y;u2[6]=c4.z; }
            { const float* wp = wbuf + (2*C3_NCH + c8)*C3_WST + ky*8;
              float4 a = *(const float4*)wp, c4 = *(const float4*)(wp+4);
              u3[0]=a.x;u3[1]=a.y;u3[2]=a.z;u3[3]=a.w;u3[4]=c4.x;u3[5]=c4.y;u3[6]=c4.z; }

            #pragma unroll
            for (int c = 0; c < 8; ++c){
                #pragma unroll
                for (int kx = 0; kx < 7; ++kx){
                    float xv = win[c+kx];
                    a1[c] += u1[kx]*xv;
                    a2[c] += u2[kx]*xv;
                    a3[c] += u3[kx]*xv;
                }
            }
        }

        float b1 = eb[e1*C_ + cc0 + c8];
        float b2 = eb[e2*C_ + cc0 + c8];
        float b3 = sb[cc0 + c8];
        size_t obase = ((size_t)b*HW_ + (size_t)(r0+trow)*W_ + (c0+colt))*C_ + cc0 + c8;
        #pragma unroll
        for (int c = 0; c < 8; ++c){
            float o1 = a1[c] + b1;
            float o2 = a2[c] + b2;
            float o3 = a3[c] + b3;
            float v = __expf(o1) + __expf(o2);
            if (v == 0.f) v = 2.220446049250313e-16f;
            out[obase + (size_t)c*C_] = __logf(v) + o3;
        }

        __syncthreads();                        // all waves done reading chunk k
        if (k < 7){ write_regs(); __syncthreads(); }
    }
}

extern "C" void kernel_launch(void* const* d_in, const int* in_sizes, int n_in,
                              void* d_out, int out_size, void* d_ws, size_t ws_size,
                              hipStream_t stream) {
    float* out = (float*)d_out;

    // ---- host-side assumption assertions -> sentinel in absmax ----
    static const int exp_sizes[8] = {16777216, 3136, 1, 131072, 25088, 512, 3136, 64};
    if (n_in != 8){ k_sentinel<<<1,64,0,stream>>>(out, 500.f); return; }
    for (int i = 0; i < 8; ++i){
        if (in_sizes[i] != exp_sizes[i]){
            k_sentinel<<<1,64,0,stream>>>(out, 600.f + 8.f*i); return;
        }
    }
    if (out_size != 16777217){ k_sentinel<<<1,64,0,stream>>>(out, 800.f); return; }
    if (ws_size < (size_t)(WS_SEL + 64)*4){ k_sentinel<<<1,64,0,stream>>>(out, 900.f); return; }

    const float* x  = (const float*)d_in[0];
    const float* rw = (const float*)d_in[1];
    const float* rb = (const float*)d_in[2];
    const float* wg = (const float*)d_in[3];
    const float* ew = (const float*)d_in[4];
    const float* eb = (const float*)d_in[5];
    const float* sw = (const float*)d_in[6];
    const float* sb = (const float*)d_in[7];
    float* wsf = (float*)d_ws;

    // Partial router outputs live in d_out (fully overwritten by k3 afterwards):
    // part[g][b][hw], g=0..7  -> 8 MB of the 64 MB output buffer.
    k1p<<<2048, 256, 0, stream>>>(x, rw, rb, out);
    kg<<<128, 256, 0, stream>>>(out, wg, wsf + WS_LOGITS);
    k2_gating<<<1, 64, 0, stream>>>(wsf + WS_LOGITS, (int*)(wsf + WS_SEL), out);
    k3_tiled<<<1024, 256, 0, stream>>>(x, ew, eb, sw, sb,
                                       (const int*)(wsf + WS_SEL), out);
}

// Round 6
// 347.071 us; speedup vs baseline: 1.7889x; 1.7889x over previous
//
#include <hip/hip_runtime.h>
#include <hip/hip_bf16.h>

#define B_  16
#define C_  64
#define H_  128
#define W_  128
#define HW_ (H_*W_)
#define E_  8

// ws layout (float offsets)
#define WS_LOGITS 0       // 128 floats
#define WS_SEL    128     // 32 ints: e1[16] then e2[16]

// ---- sentinel: encode a failed host-side assertion in the absmax ----
__global__ void k_sentinel(float* out, float v){
    if (blockIdx.x == 0 && threadIdx.x == 0) out[0] = v;
}

// ================= k1p: router conv, channel-split partials =================
// 16x64 pixel tile, 8 channel groups of 8 channels (2048 blocks, 8/CU).
// Direct global->LDS staging (no reg staging, no min-wave forcing -> no spills).
// Double-buffered LDS: stage ch+1 into other buffer while computing ch.
// Partial r for group g goes to part[g*B*HW + b*HW + hw]  (part = d_out scratch).
#define R_TH 16
#define R_TW 64
#define R_HH (R_TH+6)    // 22
#define R_HW (R_TW+6)    // 70
#define R_LS 76          // LDS row stride
#define R_HN (R_HH*R_HW) // 1540
#define RG_CH 8          // channels per group
#define RG_N  8          // groups

__device__ __forceinline__ void r_stage(const float* __restrict__ xc, float* dst,
                                        int row0, int col0, int tid){
    for (int i = tid; i < R_HN; i += 256){
        int hr = i / R_HW, hc = i - hr*R_HW;
        int gr = row0 + hr - 3, gc = col0 + hc - 3;
        float v = 0.f;
        if ((unsigned)gr < (unsigned)H_ && (unsigned)gc < (unsigned)W_)
            v = xc[gr*W_+gc];
        dst[hr*R_LS+hc] = v;
    }
}

__global__ __launch_bounds__(256) void k1p(const float* __restrict__ x,
                                           const float* __restrict__ rw,
                                           const float* __restrict__ rb,
                                           float* __restrict__ part){
    __shared__ __align__(16) float tile[2][R_HH*R_LS];   // 2 x 6688 B = 13.4 KB

    int id = blockIdx.x;
    int g   = id & 7; id >>= 3;      // channel group (8)
    int txt = id & 1; id >>= 1;      // col half
    int tyt = id & 7; id >>= 3;      // 16-row band
    int b   = id;                    // 16
    int row0 = tyt*R_TH, col0 = txt*R_TW;
    int tx = threadIdx.x & 15, ty = threadIdx.x >> 4;
    int row  = row0 + ty;
    int colb = col0 + 4*tx;

    const float* xg  = x  + ((size_t)(b*C_) + g*RG_CH)*HW_;
    const float* wgr = rw + g*RG_CH*49;

    float acc[4] = {0.f,0.f,0.f,0.f};

    r_stage(xg, tile[0], row0, col0, threadIdx.x);
    __syncthreads();

    for (int ch = 0; ch < RG_CH; ++ch){
        // stage next channel into the buffer nobody is reading
        if (ch + 1 < RG_CH)
            r_stage(xg + (size_t)(ch+1)*HW_, tile[(ch+1)&1], row0, col0, threadIdx.x);

        const float* wr = wgr + ch*49;           // block-uniform -> SGPR
        const float* tb = tile[ch&1];
        #pragma unroll
        for (int ky = 0; ky < 7; ++ky){
            const float* trp = &tb[(ty+ky)*R_LS + 4*tx];
            float4 va = *(const float4*)(trp);
            float4 vb = *(const float4*)(trp+4);
            float2 vc = *(const float2*)(trp+8);
            float win[10] = {va.x,va.y,va.z,va.w, vb.x,vb.y,vb.z,vb.w, vc.x,vc.y};
            #pragma unroll
            for (int kx = 0; kx < 7; ++kx){
                float w = wr[ky*7+kx];
                acc[0] += w*win[kx+0];
                acc[1] += w*win[kx+1];
                acc[2] += w*win[kx+2];
                acc[3] += w*win[kx+3];
            }
        }
        __syncthreads();   // staging of ch+1 done AND all reads of ch done
    }

    if (g == 0){
        float rbv = rb[0];
        acc[0]+=rbv; acc[1]+=rbv; acc[2]+=rbv; acc[3]+=rbv;
    }
    float* pr = part + (size_t)g*(B_*HW_);
    size_t base = (size_t)b*HW_ + (size_t)row*W_ + colb;
    #pragma unroll
    for (int p = 0; p < 4; ++p) pr[base+p] = acc[p];
}

// ---- kg: logits[b,e] = sum_hw (sum_g part[g,b,hw]) * wg[hw,e] ----
__global__ __launch_bounds__(256) void kg(const float* __restrict__ part,
                                          const float* __restrict__ wg,
                                          float* __restrict__ logits){
    __shared__ float red[256];
    int b = blockIdx.x >> 3, e = blockIdx.x & 7;   // 128 blocks
    const float* p0 = part + (size_t)b*HW_;
    float s = 0.f;
    for (int hw = threadIdx.x; hw < HW_; hw += 256){
        float rv = 0.f;
        #pragma unroll
        for (int gg = 0; gg < RG_N; ++gg)
            rv += p0[hw + (size_t)gg*(B_*HW_)];
        s += rv * wg[(size_t)hw*E_ + e];
    }
    red[threadIdx.x] = s;
    __syncthreads();
    for (int off = 128; off > 0; off >>= 1){
        if (threadIdx.x < off) red[threadIdx.x] += red[threadIdx.x + off];
        __syncthreads();
    }
    if (threadIdx.x == 0) logits[b*E_+e] = red[0];
}

// ---- k2: parallel top-2 gating + loss ----
__global__ void k2_gating(const float* __restrict__ logits,
                          int* __restrict__ sel,
                          float* __restrict__ out){
    __shared__ float g1s[B_], g2s[B_];
    __shared__ int   i1s[B_], i2s[B_];
    __shared__ float impS[E_], cntS[E_];
    int t = threadIdx.x;
    if (t < B_){
        const float* l = logits + t*E_;
        int i1 = 0;
        #pragma unroll
        for (int e = 1; e < E_; ++e) if (l[e] > l[i1]) i1 = e;   // ties -> lowest idx
        int i2 = (i1 == 0) ? 1 : 0;
        #pragma unroll
        for (int e = 0; e < E_; ++e) if (e != i1 && l[e] > l[i2]) i2 = e;
        float ex = expf(l[i2] - l[i1]);
        float g1 = 1.f/(1.f+ex), g2 = ex/(1.f+ex);
        sel[t] = i1; sel[B_ + t] = i2;
        g1s[t] = g1; g2s[t] = g2; i1s[t] = i1; i2s[t] = i2;
    }
    __syncthreads();
    if (t < E_){
        float im = 0.f, cn = 0.f;
        #pragma unroll
        for (int bb = 0; bb < B_; ++bb){
            im += (i1s[bb]==t ? g1s[bb] : 0.f) + (i2s[bb]==t ? g2s[bb] : 0.f);
            cn += (i1s[bb]==t ? 1.f : 0.f)     + (i2s[bb]==t ? 1.f : 0.f);
        }
        impS[t] = im; cntS[t] = cn;
    }
    __syncthreads();
    if (t == 0){
        float m1 = 0.f, m2 = 0.f;
        for (int e = 0; e < E_; ++e){ m1 += impS[e]; m2 += cntS[e]; }
        m1 *= (1.f/E_); m2 *= (1.f/E_);
        float v1 = 0.f, v2 = 0.f;
        for (int e = 0; e < E_; ++e){
            float d1 = impS[e] - m1; v1 += d1*d1;
            float d2 = cntS[e] - m2; v2 += d2*d2;
        }
        v1 *= (1.f/(E_-1)); v2 *= (1.f/(E_-1));
        float loss = (v1/(m1*m1 + 1e-10f) + v2/(m2*m2 + 1e-10f)) * 0.01f;
        out[(size_t)B_*HW_*C_] = loss;
    }
}

// ================= k3: tiled experts+shared conv + LSE combine =================
// 16x16 pixel tile, 8 chunks of 8 channels. LDS 25 KB (single buffer).
// Thread = (c8, trow, col-half): 8 output cols/thread -> 24 accs live.
// Direct global->LDS staging; no launch-bounds forcing -> no spills.
#define C3_NCH 8
#define C3_CS  28                 // LDS col stride (22 used)
#define C3_CHS (22*C3_CS)         // 616 floats/channel plane
#define C3_WST 56                 // 7 ky x 8 (kx 0..6 + zero pad)
#define C3_TN  (C3_NCH*22*22)     // 3872
#define C3_WN  (3*C3_NCH*C3_WST)  // 1344

__global__ __launch_bounds__(256) void k3_tiled(const float* __restrict__ x,
                                                const float* __restrict__ ew,
                                                const float* __restrict__ eb,
                                                const float* __restrict__ sw,
                                                const float* __restrict__ sb,
                                                const int* __restrict__ sel,
                                                float* __restrict__ out){
    __shared__ __align__(16) float tile[C3_NCH*C3_CHS];   // 4928 f = 19.7 KB
    __shared__ __align__(16) float wbuf[C3_WN];           // 1344 f =  5.4 KB

    int id = blockIdx.x;
    int cx = id & 7; id >>= 3;
    int cy = id & 7; id >>= 3;
    int b  = id;                           // 1024 blocks
    int r0 = cy*16, c0 = cx*16;

    int c8   = threadIdx.x & 7;            // channel within chunk
    int slot = threadIdx.x >> 3;           // 0..31
    int trow = slot >> 1;                  // 0..15
    int colt = (slot & 1) * 8;             // col half: 0 or 8

    int e1 = sel[b], e2 = sel[B_ + b];

    for (int k = 0; k < 8; ++k){
        int cc0 = k*C3_NCH;
        __syncthreads();                   // everyone done reading chunk k-1
        // stage x: 8 ch x 22 x 22 (stride-28 rows)
        for (int i = threadIdx.x; i < C3_TN; i += 256){
            int ci = i / 484; int rem = i - ci*484;
            int hr = rem / 22, hc = rem - hr*22;
            int gr = r0 + hr - 3, gc = c0 + hc - 3;
            float v = 0.f;
            if ((unsigned)gr < (unsigned)H_ && (unsigned)gc < (unsigned)W_)
                v = x[((size_t)(b*C_ + cc0 + ci))*HW_ + gr*W_ + gc];
            tile[ci*C3_CHS + hr*C3_CS + hc] = v;
        }
        // stage weights: 3 x 8ch x (7ky x 8), kx==7 zero-padded
        for (int i = threadIdx.x; i < C3_WN; i += 256){
            int which = i / 448;           // 8ch*56
            int rem = i - which*448;
            int wc = rem / C3_WST;
            int tt = rem - wc*C3_WST;
            int ky = tt >> 3, kx = tt & 7;
            float v = 0.f;
            if (kx < 7){
                int tap = ky*7 + kx;
                if (which == 0)      v = ew[((size_t)(e1*C_ + cc0 + wc))*49 + tap];
                else if (which == 1) v = ew[((size_t)(e2*C_ + cc0 + wc))*49 + tap];
                else                 v = sw[((size_t)(cc0 + wc))*49 + tap];
            }
            wbuf[i] = v;
        }
        __syncthreads();

        float a1[8], a2[8], a3[8];
        #pragma unroll
        for (int c = 0; c < 8; ++c){ a1[c]=0.f; a2[c]=0.f; a3[c]=0.f; }

        const float* tb = tile + c8*C3_CHS;
        #pragma unroll
        for (int ky = 0; ky < 7; ++ky){
            const float* trp = tb + (trow+ky)*C3_CS + colt;
            float win[16];
            #pragma unroll
            for (int q = 0; q < 4; ++q){
                float4 v4 = *(const float4*)(trp + 4*q);
                win[4*q+0]=v4.x; win[4*q+1]=v4.y; win[4*q+2]=v4.z; win[4*q+3]=v4.w;
            }
            float u1[7], u2[7], u3[7];
            { const float* wp = wbuf + (0*C3_NCH + c8)*C3_WST + ky*8;
              float4 a = *(const float4*)wp, c4 = *(const float4*)(wp+4);
              u1[0]=a.x;u1[1]=a.y;u1[2]=a.z;u1[3]=a.w;u1[4]=c4.x;u1[5]=c4.y;u1[6]=c4.z; }
            { const float* wp = wbuf + (1*C3_NCH + c8)*C3_WST + ky*8;
              float4 a = *(const float4*)wp, c4 = *(const float4*)(wp+4);
              u2[0]=a.x;u2[1]=a.y;u2[2]=a.z;u2[3]=a.w;u2[4]=c4.x;u2[5]=c4.y;u2[6]=c4.z; }
            { const float* wp = wbuf + (2*C3_NCH + c8)*C3_WST + ky*8;
              float4 a = *(const float4*)wp, c4 = *(const float4*)(wp+4);
              u3[0]=a.x;u3[1]=a.y;u3[2]=a.z;u3[3]=a.w;u3[4]=c4.x;u3[5]=c4.y;u3[6]=c4.z; }

            #pragma unroll
            for (int c = 0; c < 8; ++c){
                #pragma unroll
                for (int kx = 0; kx < 7; ++kx){
                    float xv = win[c+kx];
                    a1[c] += u1[kx]*xv;
                    a2[c] += u2[kx]*xv;
                    a3[c] += u3[kx]*xv;
                }
            }
        }

        float b1 = eb[e1*C_ + cc0 + c8];
        float b2 = eb[e2*C_ + cc0 + c8];
        float b3 = sb[cc0 + c8];
        size_t obase = ((size_t)b*HW_ + (size_t)(r0+trow)*W_ + (c0+colt))*C_ + cc0 + c8;
        #pragma unroll
        for (int c = 0; c < 8; ++c){
            float o1 = a1[c] + b1;
            float o2 = a2[c] + b2;
            float o3 = a3[c] + b3;
            float v = __expf(o1) + __expf(o2);
            if (v == 0.f) v = 2.220446049250313e-16f;
            out[obase + (size_t)c*C_] = __logf(v) + o3;
        }
    }
}

extern "C" void kernel_launch(void* const* d_in, const int* in_sizes, int n_in,
                              void* d_out, int out_size, void* d_ws, size_t ws_size,
                              hipStream_t stream) {
    float* out = (float*)d_out;

    // ---- host-side assumption assertions -> sentinel in absmax ----
    static const int exp_sizes[8] = {16777216, 3136, 1, 131072, 25088, 512, 3136, 64};
    if (n_in != 8){ k_sentinel<<<1,64,0,stream>>>(out, 500.f); return; }
    for (int i = 0; i < 8; ++i){
        if (in_sizes[i] != exp_sizes[i]){
            k_sentinel<<<1,64,0,stream>>>(out, 600.f + 8.f*i); return;
        }
    }
    if (out_size != 16777217){ k_sentinel<<<1,64,0,stream>>>(out, 800.f); return; }
    if (ws_size < (size_t)(WS_SEL + 64)*4){ k_sentinel<<<1,64,0,stream>>>(out, 900.f); return; }

    const float* x  = (const float*)d_in[0];
    const float* rw = (const float*)d_in[1];
    const float* rb = (const float*)d_in[2];
    const float* wg = (const float*)d_in[3];
    const float* ew = (const float*)d_in[4];
    const float* eb = (const float*)d_in[5];
    const float* sw = (const float*)d_in[6];
    const float* sb = (const float*)d_in[7];
    float* wsf = (float*)d_ws;

    // Partial router outputs live in d_out (fully overwritten by k3 afterwards):
    // part[g][b][hw], g=0..7  -> 8 MB of the 64 MB output buffer.
    k1p<<<2048, 256, 0, stream>>>(x, rw, rb, out);
    kg<<<128, 256, 0, stream>>>(out, wg, wsf + WS_LOGITS);
    k2_gating<<<1, 64, 0, stream>>>(wsf + WS_LOGITS, (int*)(wsf + WS_SEL), out);
    k3_tiled<<<1024, 256, 0, stream>>>(x, ew, eb, sw, sb,
                                       (const int*)(wsf + WS_SEL), out);
}

// Round 7
// 311.632 us; speedup vs baseline: 1.9923x; 1.1137x over previous
//
#include <hip/hip_runtime.h>
#include <hip/hip_bf16.h>

#define B_  16
#define C_  64
#define H_  128
#define W_  128
#define HW_ (H_*W_)
#define E_  8

// ws layout (float offsets)
#define WS_LOGITS 0       // 128 floats (unused now, kept for layout stability)
#define WS_SEL    128     // 32 ints: e1[16] then e2[16]
#define WS_PART   256     // 2048*8 floats: per-block partial logits

// ---- sentinel: encode a failed host-side assertion in the absmax ----
__global__ void k_sentinel(float* out, float v){
    if (blockIdx.x == 0 && threadIdx.x == 0) out[0] = v;
}

// ================= k1p: router conv + fused gating dot =================
// 16x64 pixel tile, 8 channel groups of 8 channels (2048 blocks, 8/CU).
// Double-buffered LDS staging. After the conv, each thread dots its 4 r-values
// with wg[px, 0..7] and the block reduces to 8 partial logits -> ws.
// Block id = b*128 + tyt*16 + txt*8 + g  (b outermost, for k2's summation).
#define R_TH 16
#define R_TW 64
#define R_HH (R_TH+6)    // 22
#define R_HW (R_TW+6)    // 70
#define R_LS 76          // LDS row stride (76 mod 32 = 12 -> bank-spread)
#define R_HN (R_HH*R_HW) // 1540
#define RG_CH 8          // channels per group
#define RG_N  8          // groups

__device__ __forceinline__ void r_stage(const float* __restrict__ xc, float* dst,
                                        int row0, int col0, int tid){
    for (int i = tid; i < R_HN; i += 256){
        int hr = i / R_HW, hc = i - hr*R_HW;
        int gr = row0 + hr - 3, gc = col0 + hc - 3;
        float v = 0.f;
        if ((unsigned)gr < (unsigned)H_ && (unsigned)gc < (unsigned)W_)
            v = xc[gr*W_+gc];
        dst[hr*R_LS+hc] = v;
    }
}

__global__ __launch_bounds__(256) void k1p(const float* __restrict__ x,
                                           const float* __restrict__ rw,
                                           const float* __restrict__ rb,
                                           const float* __restrict__ wg,
                                           float* __restrict__ partial){
    __shared__ __align__(16) float tile[2][R_HH*R_LS];   // 2 x 6688 B = 13.4 KB
    __shared__ float pred[4][E_];

    int id = blockIdx.x;
    int g   = id & 7; id >>= 3;      // channel group (8)
    int txt = id & 1; id >>= 1;      // col half
    int tyt = id & 7; id >>= 3;      // 16-row band
    int b   = id;                    // 16
    int row0 = tyt*R_TH, col0 = txt*R_TW;
    int tx = threadIdx.x & 15, ty = threadIdx.x >> 4;
    int row  = row0 + ty;
    int colb = col0 + 4*tx;

    const float* xg  = x  + ((size_t)(b*C_) + g*RG_CH)*HW_;
    const float* wgr = rw + g*RG_CH*49;

    float acc[4] = {0.f,0.f,0.f,0.f};

    r_stage(xg, tile[0], row0, col0, threadIdx.x);
    __syncthreads();

    for (int ch = 0; ch < RG_CH; ++ch){
        // stage next channel into the buffer nobody is reading
        if (ch + 1 < RG_CH)
            r_stage(xg + (size_t)(ch+1)*HW_, tile[(ch+1)&1], row0, col0, threadIdx.x);

        const float* wr = wgr + ch*49;           // block-uniform -> SGPR
        const float* tb = tile[ch&1];
        #pragma unroll
        for (int ky = 0; ky < 7; ++ky){
            const float* trp = &tb[(ty+ky)*R_LS + 4*tx];
            float4 va = *(const float4*)(trp);
            float4 vb = *(const float4*)(trp+4);
            float2 vc = *(const float2*)(trp+8);
            float win[10] = {va.x,va.y,va.z,va.w, vb.x,vb.y,vb.z,vb.w, vc.x,vc.y};
            #pragma unroll
            for (int kx = 0; kx < 7; ++kx){
                float w = wr[ky*7+kx];
                acc[0] += w*win[kx+0];
                acc[1] += w*win[kx+1];
                acc[2] += w*win[kx+2];
                acc[3] += w*win[kx+3];
            }
        }
        __syncthreads();   // staging of ch+1 done AND all reads of ch done
    }

    if (g == 0){
        float rbv = rb[0];
        acc[0]+=rbv; acc[1]+=rbv; acc[2]+=rbv; acc[3]+=rbv;
    }

    // ---- fused gating dot: pl[e] = sum_px acc[px] * wg[px, e] ----
    const float* wrow = wg + (size_t)(row*W_ + colb)*E_;   // 128B-aligned
    float pl[E_];
    #pragma unroll
    for (int e = 0; e < E_; ++e) pl[e] = 0.f;
    #pragma unroll
    for (int p = 0; p < 4; ++p){
        float4 wa = *(const float4*)(wrow + p*E_);
        float4 wb = *(const float4*)(wrow + p*E_ + 4);
        float a = acc[p];
        pl[0] += a*wa.x; pl[1] += a*wa.y; pl[2] += a*wa.z; pl[3] += a*wa.w;
        pl[4] += a*wb.x; pl[5] += a*wb.y; pl[6] += a*wb.z; pl[7] += a*wb.w;
    }
    // wave reduce (64 lanes)
    #pragma unroll
    for (int off = 32; off > 0; off >>= 1){
        #pragma unroll
        for (int e = 0; e < E_; ++e) pl[e] += __shfl_down(pl[e], off, 64);
    }
    int lane = threadIdx.x & 63, wv = threadIdx.x >> 6;
    if (lane == 0){
        #pragma unroll
        for (int e = 0; e < E_; ++e) pred[wv][e] = pl[e];
    }
    __syncthreads();
    if (threadIdx.x < E_){
        int e = threadIdx.x;
        float s = pred[0][e] + pred[1][e] + pred[2][e] + pred[3][e];
        partial[(size_t)blockIdx.x*E_ + e] = s;
    }
}

// ---- k2: sum partials -> logits, then parallel top-2 gating + loss ----
__global__ void k2_gating(const float* __restrict__ partial,
                          int* __restrict__ sel,
                          float* __restrict__ out){
    __shared__ float lg[B_*E_];
    __shared__ float g1s[B_], g2s[B_];
    __shared__ int   i1s[B_], i2s[B_];
    __shared__ float impS[E_], cntS[E_];
    int t = threadIdx.x;                 // 256 threads
    if (t < B_*E_){
        int b = t >> 3, e = t & 7;
        const float* pp = partial + ((size_t)b*128)*E_ + e;
        float s = 0.f;
        #pragma unroll 4
        for (int j = 0; j < 128; ++j) s += pp[(size_t)j*E_];
        lg[t] = s;
    }
    __syncthreads();
    if (t < B_){
        const float* l = lg + t*E_;
        int i1 = 0;
        #pragma unroll
        for (int e = 1; e < E_; ++e) if (l[e] > l[i1]) i1 = e;   // ties -> lowest idx
        int i2 = (i1 == 0) ? 1 : 0;
        #pragma unroll
        for (int e = 0; e < E_; ++e) if (e != i1 && l[e] > l[i2]) i2 = e;
        float ex = expf(l[i2] - l[i1]);
        float g1 = 1.f/(1.f+ex), g2 = ex/(1.f+ex);
        sel[t] = i1; sel[B_ + t] = i2;
        g1s[t] = g1; g2s[t] = g2; i1s[t] = i1; i2s[t] = i2;
    }
    __syncthreads();
    if (t < E_){
        float im = 0.f, cn = 0.f;
        #pragma unroll
        for (int bb = 0; bb < B_; ++bb){
            im += (i1s[bb]==t ? g1s[bb] : 0.f) + (i2s[bb]==t ? g2s[bb] : 0.f);
            cn += (i1s[bb]==t ? 1.f : 0.f)     + (i2s[bb]==t ? 1.f : 0.f);
        }
        impS[t] = im; cntS[t] = cn;
    }
    __syncthreads();
    if (t == 0){
        float m1 = 0.f, m2 = 0.f;
        for (int e = 0; e < E_; ++e){ m1 += impS[e]; m2 += cntS[e]; }
        m1 *= (1.f/E_); m2 *= (1.f/E_);
        float v1 = 0.f, v2 = 0.f;
        for (int e = 0; e < E_; ++e){
            float d1 = impS[e] - m1; v1 += d1*d1;
            float d2 = cntS[e] - m2; v2 += d2*d2;
        }
        v1 *= (1.f/(E_-1)); v2 *= (1.f/(E_-1));
        float loss = (v1/(m1*m1 + 1e-10f) + v2/(m2*m2 + 1e-10f)) * 0.01f;
        out[(size_t)B_*HW_*C_] = loss;
    }
}

// ================= k3: tiled experts+shared conv + LSE combine =================
// 16x16 pixel tile, 2 half-blocks of 4 chunks x 8 channels (2048 blocks).
// Plane stride 620 (mod 32 = 12) and weight stride 60 (mod 32 = 28) spread the
// 8 c8-lanes across all 32 banks -> conflict-free ds_read_b128.
#define C3_NCH 8
#define C3_CS  28                 // LDS col stride within a row (22 used)
#define C3_CHS 620                // channel plane stride: 22*28 + 4  (mod 32 = 12)
#define C3_WST 60                 // weight stride per channel (mod 32 = 28)
#define C3_TN  (C3_NCH*22*22)     // 3872 staged x elements
#define C3_WN  (3*C3_NCH*C3_WST)  // 1440 staged weight slots

__global__ __launch_bounds__(256) void k3_tiled(const float* __restrict__ x,
                                                const float* __restrict__ ew,
                                                const float* __restrict__ eb,
                                                const float* __restrict__ sw,
                                                const float* __restrict__ sb,
                                                const int* __restrict__ sel,
                                                float* __restrict__ out){
    __shared__ __align__(16) float tile[C3_NCH*C3_CHS];   // 4960 f = 19.84 KB
    __shared__ __align__(16) float wbuf[C3_WN];           // 1440 f =  5.76 KB

    int id = blockIdx.x;
    int half = id & 1; id >>= 1;
    int cx = id & 7; id >>= 3;
    int cy = id & 7; id >>= 3;
    int b  = id;                           // 16  -> 2048 blocks total
    int r0 = cy*16, c0 = cx*16;

    int c8   = threadIdx.x & 7;            // channel within chunk
    int slot = threadIdx.x >> 3;           // 0..31
    int trow = slot >> 1;                  // 0..15
    int colt = (slot & 1) * 8;             // col half: 0 or 8

    int e1 = sel[b], e2 = sel[B_ + b];

    for (int kk = 0; kk < 4; ++kk){
        int cc0 = (half*4 + kk)*C3_NCH;
        __syncthreads();                   // everyone done reading prev chunk
        // stage x: 8 ch x 22 x 22 (row stride 28, plane stride 620)
        for (int i = threadIdx.x; i < C3_TN; i += 256){
            int ci = i / 484; int rem = i - ci*484;
            int hr = rem / 22, hc = rem - hr*22;
            int gr = r0 + hr - 3, gc = c0 + hc - 3;
            float v = 0.f;
            if ((unsigned)gr < (unsigned)H_ && (unsigned)gc < (unsigned)W_)
                v = x[((size_t)(b*C_ + cc0 + ci))*HW_ + gr*W_ + gc];
            tile[ci*C3_CHS + hr*C3_CS + hc] = v;
        }
        // stage weights: 3 x 8ch x 60 (7ky x 8 used, rest zero)
        for (int i = threadIdx.x; i < C3_WN; i += 256){
            int which = i / (C3_NCH*C3_WST);
            int rem = i - which*(C3_NCH*C3_WST);
            int wc = rem / C3_WST;
            int tt = rem - wc*C3_WST;
            int ky = tt >> 3, kx = tt & 7;
            float v = 0.f;
            if (ky < 7 && kx < 7){
                int tap = ky*7 + kx;
                if (which == 0)      v = ew[((size_t)(e1*C_ + cc0 + wc))*49 + tap];
                else if (which == 1) v = ew[((size_t)(e2*C_ + cc0 + wc))*49 + tap];
                else                 v = sw[((size_t)(cc0 + wc))*49 + tap];
            }
            wbuf[i] = v;
        }
        __syncthreads();

        float a1[8], a2[8], a3[8];
        #pragma unroll
        for (int c = 0; c < 8; ++c){ a1[c]=0.f; a2[c]=0.f; a3[c]=0.f; }

        const float* tb = tile + c8*C3_CHS;
        #pragma unroll
        for (int ky = 0; ky < 7; ++ky){
            const float* trp = tb + (trow+ky)*C3_CS + colt;
            float win[16];
            #pragma unroll
            for (int q = 0; q < 4; ++q){
                float4 v4 = *(const float4*)(trp + 4*q);
                win[4*q+0]=v4.x; win[4*q+1]=v4.y; win[4*q+2]=v4.z; win[4*q+3]=v4.w;
            }
            float u1[7], u2[7], u3[7];
            { const float* wp = wbuf + (0*C3_NCH + c8)*C3_WST + ky*8;
              float4 a = *(const float4*)wp, c4 = *(const float4*)(wp+4);
              u1[0]=a.x;u1[1]=a.y;u1[2]=a.z;u1[3]=a.w;u1[4]=c4.x;u1[5]=c4.y;u1[6]=c4.z; }
            { const float* wp = wbuf + (1*C3_NCH + c8)*C3_WST + ky*8;
              float4 a = *(const float4*)wp, c4 = *(const float4*)(wp+4);
              u2[0]=a.x;u2[1]=a.y;u2[2]=a.z;u2[3]=a.w;u2[4]=c4.x;u2[5]=c4.y;u2[6]=c4.z; }
            { const float* wp = wbuf + (2*C3_NCH + c8)*C3_WST + ky*8;
              float4 a = *(const float4*)wp, c4 = *(const float4*)(wp+4);
              u3[0]=a.x;u3[1]=a.y;u3[2]=a.z;u3[3]=a.w;u3[4]=c4.x;u3[5]=c4.y;u3[6]=c4.z; }

            #pragma unroll
            for (int c = 0; c < 8; ++c){
                #pragma unroll
                for (int kx = 0; kx < 7; ++kx){
                    float xv = win[c+kx];
                    a1[c] += u1[kx]*xv;
                    a2[c] += u2[kx]*xv;
                    a3[c] += u3[kx]*xv;
                }
            }
        }

        float b1 = eb[e1*C_ + cc0 + c8];
        float b2 = eb[e2*C_ + cc0 + c8];
        float b3 = sb[cc0 + c8];
        size_t obase = ((size_t)b*HW_ + (size_t)(r0+trow)*W_ + (c0+colt))*C_ + cc0 + c8;
        #pragma unroll
        for (int c = 0; c < 8; ++c){
            float o1 = a1[c] + b1;
            float o2 = a2[c] + b2;
            float o3 = a3[c] + b3;
            float v = __expf(o1) + __expf(o2);
            if (v == 0.f) v = 2.220446049250313e-16f;
            out[obase + (size_t)c*C_] = __logf(v) + o3;
        }
    }
}

extern "C" void kernel_launch(void* const* d_in, const int* in_sizes, int n_in,
                              void* d_out, int out_size, void* d_ws, size_t ws_size,
                              hipStream_t stream) {
    float* out = (float*)d_out;

    // ---- host-side assumption assertions -> sentinel in absmax ----
    static const int exp_sizes[8] = {16777216, 3136, 1, 131072, 25088, 512, 3136, 64};
    if (n_in != 8){ k_sentinel<<<1,64,0,stream>>>(out, 500.f); return; }
    for (int i = 0; i < 8; ++i){
        if (in_sizes[i] != exp_sizes[i]){
            k_sentinel<<<1,64,0,stream>>>(out, 600.f + 8.f*i); return;
        }
    }
    if (out_size != 16777217){ k_sentinel<<<1,64,0,stream>>>(out, 800.f); return; }
    if (ws_size < (size_t)(WS_PART + 2048*E_)*4){ k_sentinel<<<1,64,0,stream>>>(out, 900.f); return; }

    const float* x  = (const float*)d_in[0];
    const float* rw = (const float*)d_in[1];
    const float* rb = (const float*)d_in[2];
    const float* wg = (const float*)d_in[3];
    const float* ew = (const float*)d_in[4];
    const float* eb = (const float*)d_in[5];
    const float* sw = (const float*)d_in[6];
    const float* sb = (const float*)d_in[7];
    float* wsf = (float*)d_ws;

    k1p<<<2048, 256, 0, stream>>>(x, rw, rb, wg, wsf + WS_PART);
    k2_gating<<<1, 256, 0, stream>>>(wsf + WS_PART, (int*)(wsf + WS_SEL), out);
    k3_tiled<<<2048, 256, 0, stream>>>(x, ew, eb, sw, sb,
                                       (const int*)(wsf + WS_SEL), out);
}